// Round 4
// baseline (14413.240 us; speedup 1.0000x reference)
//
#include <hip/hip_runtime.h>
#include <cmath>
#include <complex>

#define BT 16   // batch tile per block
#define NP 11   // number of tensor-product paths

// ---- path metadata (compile-time) ----------------------------------------
// paths in reference order: (i1,i2,io) =
// (0,0,0),(0,1,1),(0,2,2),(1,0,1),(1,1,0),(1,1,2),(1,2,1),(2,0,2),(2,1,1),(2,2,0),(2,2,2)
constexpr int P_N1[NP]   = {1,1,1, 3,3,3,3, 5,5,5,5};              // 2*l1+1
constexpr int P_N2[NP]   = {1,3,5, 1,3,3,5, 1,3,5,5};              // 2*l2+1
constexpr int P_NO[NP]   = {1,3,5, 3,1,5,3, 5,3,1,5};              // 2*lo+1
constexpr int P_S1[NP]   = {0,0,0, 128,128,128,128, 512,512,512,512}; // x1 offset
constexpr int P_S2[NP]   = {0,1,4, 0,1,1,4, 0,1,4,4};              // x2 offset
constexpr int P_MOFF[NP] = {0,1,4,9,18,21,36,45,70,85,90};         // M LDS offsets (sizes no*n1, total 115)
constexpr int P_W3J[NP]  = {0,1,10,35,44,53,98,143,168,213,238};   // w3j offsets (sizes n1*n2*no, total 363)

// io-major pass structure: every path in a pass has the same no = 2*lo+1.
// pass 0 (no=1): paths 0,4,9   pass 1 (no=3): 1,3,6,8   pass 2 (no=5): 2,5,7,10
constexpr int PASS_N[3]        = {3,4,4};
constexpr int PASS_PATHS[3][4] = {{0,4,9,0},{1,3,6,8},{2,5,7,10}};
constexpr int PASS_NO[3]       = {1,3,5};

#define YSTRIDE 388   // per-b ylds stride: 3*128+4 (max 3 k-slots resident; pad 4)

struct TPConst {
    float w3j[363];
    float sqa[11];
};

// ---- host-side exact mirror of the reference w3j computation -------------
namespace {

double hfact(int n) { double r = 1.0; for (int i = 2; i <= n; ++i) r *= (double)i; return r; }

void hsu2cg(int j1, int j2, int j3, double* C) {
    const int d2 = 2*j2+1, d3 = 2*j3+1, d1 = 2*j1+1;
    for (int i = 0; i < d1*d2*d3; ++i) C[i] = 0.0;
    for (int m1 = -j1; m1 <= j1; ++m1)
        for (int m2 = -j2; m2 <= j2; ++m2) {
            const int m3 = m1 + m2;
            if (m3 < -j3 || m3 > j3) continue;
            double pref = std::sqrt((2*j3+1) * hfact(j3+j1-j2) * hfact(j3-j1+j2) * hfact(j1+j2-j3) / hfact(j1+j2+j3+1));
            pref *= std::sqrt(hfact(j3+m3)*hfact(j3-m3)*hfact(j1-m1)*hfact(j1+m1)*hfact(j2-m2)*hfact(j2+m2));
            double s = 0.0;
            for (int k = 0; k <= j1+j2-j3; ++k) {
                if (j1-m1-k < 0 || j2+m2-k < 0 || j3-j2+m1+k < 0 || j3-j1-m2+k < 0) continue;
                double d = hfact(k)*hfact(j1+j2-j3-k)*hfact(j1-m1-k)*hfact(j2+m2-k)*hfact(j3-j2+m1+k)*hfact(j3-j1-m2+k);
                s += ((k & 1) ? -1.0 : 1.0) / d;
            }
            C[((j1+m1)*d2 + (j2+m2))*d3 + (j3+m3)] = pref * s;
        }
}

void hrealbasis(int l, std::complex<double>* q) {  // (2l+1)x(2l+1), row-major
    const int d = 2*l+1;
    for (int i = 0; i < d*d; ++i) q[i] = 0.0;
    const double is2 = 1.0 / std::sqrt(2.0);
    for (int m = -l; m < 0; ++m) {
        q[(l+m)*d + (l - m)] = is2;                                  // l+|m| = l-m for m<0
        q[(l+m)*d + (l + m)] = std::complex<double>(0.0, -is2);      // l-|m| = l+m
    }
    q[l*d + l] = 1.0;
    for (int m = 1; m <= l; ++m) {
        const double sgn = (m & 1) ? -1.0 : 1.0;
        q[(l+m)*d + (l + m)] = sgn * is2;
        q[(l+m)*d + (l - m)] = std::complex<double>(0.0, sgn * is2);
    }
    std::complex<double> ph(1.0, 0.0);
    const std::complex<double> mi(0.0, -1.0);
    for (int i = 0; i < l; ++i) ph *= mi;   // (-i)^l
    for (int i = 0; i < d*d; ++i) q[i] *= ph;
}

void hw3j(int l1, int l2, int l3, float* out) {
    const int d1 = 2*l1+1, d2 = 2*l2+1, d3 = 2*l3+1;
    double C[125];
    hsu2cg(l1, l2, l3, C);
    std::complex<double> Q1[25], Q2[25], Q3[25];
    hrealbasis(l1, Q1); hrealbasis(l2, Q2); hrealbasis(l3, Q3);
    double R[125]; double norm2 = 0.0;
    for (int j = 0; j < d1; ++j)
        for (int l = 0; l < d2; ++l)
            for (int m = 0; m < d3; ++m) {
                std::complex<double> s(0.0, 0.0);
                for (int i = 0; i < d1; ++i)
                    for (int k = 0; k < d2; ++k)
                        for (int n = 0; n < d3; ++n)
                            s += Q1[i*d1 + j] * Q2[k*d2 + l] * std::conj(Q3[n*d3 + m]) * C[(i*d2 + k)*d3 + n];
                R[(j*d2 + l)*d3 + m] = s.real();
                norm2 += s.real() * s.real();
            }
    const double inv = 1.0 / std::sqrt(norm2);
    for (int i = 0; i < d1*d2*d3; ++i) out[i] = (float)(R[i] * inv);
}

void fill_const(TPConst& tc) {
    const int L1[NP] = {0,0,0,1,1,1,1,2,2,2,2};
    const int L2[NP] = {0,1,2,0,1,1,2,0,1,2,2};
    const int LO[NP] = {0,1,2,1,0,2,1,2,1,0,2};
    const double den[3] = {384.0, 512.0, 512.0};   // path_normalization='element'
    for (int p = 0; p < NP; ++p) {
        hw3j(L1[p], L2[p], LO[p], tc.w3j + P_W3J[p]);
        tc.sqa[p] = (float)std::sqrt((2.0*LO[p] + 1.0) / den[LO[p]]);
    }
}

}  // namespace

// ---- device kernel --------------------------------------------------------
// Structure (round 4): io-major passes + k-split of the no=5 paths.
//  - io-major: acc[8][no] peaks at 40 regs (was acc[8][9]=72) -> kills the
//    round-3 spill (WRITE_SIZE was +16 MiB at cap 128).
//  - k-split (3+2) of no=5 paths: ylds stride 644->388 floats; LDS
//    48640->32256 B -> 4-5 blocks/CU (was 3). Cost: one extra u-sweep of W
//    loads for the 4 io=2 paths + 8 extra barriers; paid for by +33% waves
//    on a latency-bound kernel.
// VGPR calibration (measured): (256,3)->cap 84: huge spill; plain->132:
// crosses 128 HW boundary, occupancy halves; (256,2)->cap 128 OK. Keep
// (256,2); pressure now ~95 so the cap is a safety net only.
__global__ __launch_bounds__(256, 2)
void tp_kernel(const float* __restrict__ x1, const float* __restrict__ x2,
               const float* __restrict__ wsg, float* __restrict__ out, TPConst tc)
{
    __shared__ float Mlds[BT][116];      // per-b M matrices (scaled), 115 used
    __shared__ float ylds[BT * YSTRIDE]; // per-(path,kh) y, layout [b][kl][u]

    const int t = threadIdx.x;
    const long b0 = (long)blockIdx.x * BT;

    // Phase A: M_p[b][k][i] = sum_j C_p[i][j][k] * x2[b][s2+j], scaled
    if (t < BT) {
        float x2v[9];
        #pragma unroll
        for (int j = 0; j < 9; ++j) x2v[j] = x2[(b0 + t)*9 + j];
        #pragma unroll
        for (int p = 0; p < NP; ++p) {
            const int n1 = P_N1[p], n2 = P_N2[p], no = P_NO[p];
            const float sqa = tc.sqa[p];
            #pragma unroll
            for (int k = 0; k < no; ++k)
                #pragma unroll
                for (int i = 0; i < n1; ++i) {
                    float m = 0.f;
                    #pragma unroll
                    for (int j = 0; j < n2; ++j)
                        m += tc.w3j[P_W3J[p] + (i*n2 + j)*no + k] * x2v[P_S2[p] + j];
                    Mlds[t][P_MOFF[p] + k*n1 + i] = m * sqa;
                }
        }
    }

    const int uy = t & 127, g = t >> 7;    // phase B: u lane + b group
    const int cb = t >> 4, tw = t & 15;    // phase C: batch + w-octet

    __syncthreads();

    #pragma unroll
    for (int pass = 0; pass < 3; ++pass) {
        const int no = PASS_NO[pass];

        float acc[8][5];
        #pragma unroll
        for (int c = 0; c < 8; ++c)
            #pragma unroll
            for (int k = 0; k < 5; ++k) acc[c][k] = 0.f;   // only [no] used; rest DCE'd

        #pragma unroll
        for (int pi = 0; pi < 4; ++pi) {
            if (pi >= PASS_N[pass]) continue;   // constant-folded
            const int p = PASS_PATHS[pass][pi];
            const int n1 = P_N1[p];
            const int nkh = (no == 5) ? 2 : 1;

            #pragma unroll
            for (int kh = 0; kh < nkh; ++kh) {
                const int k0 = kh * 3;
                const int nok = ((no < k0 + 3) ? no : (k0 + 3)) - k0;   // 1,3 or 3,2

                // Phase B: ylds[b][kl][u] = sum_i M[b][k0+kl][i] * x1[b, s1+u*n1+i]
                #pragma unroll
                for (int bb = 0; bb < 8; ++bb) {
                    const int b = g*8 + bb;
                    const float* xp = x1 + (b0 + b)*1152 + P_S1[p] + uy*n1;
                    float xv[5];
                    #pragma unroll
                    for (int i = 0; i < n1; ++i) xv[i] = xp[i];
                    #pragma unroll
                    for (int kl = 0; kl < nok; ++kl) {
                        const int k = k0 + kl;
                        float yv = 0.f;
                        #pragma unroll
                        for (int i = 0; i < n1; ++i)
                            yv += Mlds[b][P_MOFF[p] + k*n1 + i] * xv[i];
                        ylds[b*YSTRIDE + kl*128 + uy] = yv;
                    }
                }
                __syncthreads();

                // Phase C: acc[c][k0+kl] += W_p[u][tw*8+c] * y[cb][kl][u]
                {
                    const float* yb = ylds + cb*YSTRIDE;
                    const float* wp = wsg + p*16384 + tw*8;
                    #pragma unroll 2
                    for (int u0 = 0; u0 < 128; u0 += 4) {
                        float4 yv4[3];
                        #pragma unroll
                        for (int kl = 0; kl < nok; ++kl)
                            yv4[kl] = *(const float4*)(yb + kl*128 + u0);
                        #pragma unroll
                        for (int j = 0; j < 4; ++j) {
                            const float4 wa = *(const float4*)(wp + (u0 + j)*128);
                            const float4 wb = *(const float4*)(wp + (u0 + j)*128 + 4);
                            #pragma unroll
                            for (int kl = 0; kl < nok; ++kl) {
                                const float y = (j == 0) ? yv4[kl].x
                                              : (j == 1) ? yv4[kl].y
                                              : (j == 2) ? yv4[kl].z
                                                         : yv4[kl].w;
                                const int k = k0 + kl;
                                acc[0][k] += wa.x * y;
                                acc[1][k] += wa.y * y;
                                acc[2][k] += wa.z * y;
                                acc[3][k] += wa.w * y;
                                acc[4][k] += wb.x * y;
                                acc[5][k] += wb.y * y;
                                acc[6][k] += wb.z * y;
                                acc[7][k] += wb.w * y;
                            }
                        }
                    }
                }
                __syncthreads();
            }
        }

        // Epilogue for this pass: out[b, so + w*no + k], w = tw*8 + c
        {
            float* op = out + (b0 + cb)*1152;
            if (pass == 0) {
                *(float4*)(op + tw*8)     = make_float4(acc[0][0], acc[1][0], acc[2][0], acc[3][0]);
                *(float4*)(op + tw*8 + 4) = make_float4(acc[4][0], acc[5][0], acc[6][0], acc[7][0]);
            } else if (pass == 1) {
                float b1[24];
                #pragma unroll
                for (int c = 0; c < 8; ++c)
                    #pragma unroll
                    for (int k = 0; k < 3; ++k) b1[c*3 + k] = acc[c][k];
                #pragma unroll
                for (int q = 0; q < 6; ++q)
                    *(float4*)(op + 128 + tw*24 + q*4) = *(const float4*)(b1 + q*4);
            } else {
                float b2[40];
                #pragma unroll
                for (int c = 0; c < 8; ++c)
                    #pragma unroll
                    for (int k = 0; k < 5; ++k) b2[c*5 + k] = acc[c][k];
                #pragma unroll
                for (int q = 0; q < 10; ++q)
                    *(float4*)(op + 512 + tw*40 + q*4) = *(const float4*)(b2 + q*4);
            }
        }
    }
}

// ---- launch ---------------------------------------------------------------
extern "C" void kernel_launch(void* const* d_in, const int* in_sizes, int n_in,
                              void* d_out, int out_size, void* d_ws, size_t ws_size,
                              hipStream_t stream) {
    const float* x1  = (const float*)d_in[0];
    const float* x2  = (const float*)d_in[1];
    const float* wsg = (const float*)d_in[2];
    float* out = (float*)d_out;
    const int B = in_sizes[0] / 1152;   // 32768

    TPConst tc;
    fill_const(tc);   // deterministic; identical on every call (graph-capture safe)

    dim3 grid(B / BT), block(256);
    hipLaunchKernelGGL(tp_kernel, grid, block, 0, stream, x1, x2, wsg, out, tc);
}

// Round 5
// 1326.993 us; speedup vs baseline: 10.8616x; 10.8616x over previous
//
#include <hip/hip_runtime.h>
#include <cmath>
#include <complex>

#define BT 16   // batch tile per block
#define NP 11   // number of tensor-product paths

// ---- path metadata (compile-time) ----------------------------------------
// paths in reference order: (i1,i2,io) =
// (0,0,0),(0,1,1),(0,2,2),(1,0,1),(1,1,0),(1,1,2),(1,2,1),(2,0,2),(2,1,1),(2,2,0),(2,2,2)
constexpr int P_N1[NP]   = {1,1,1, 3,3,3,3, 5,5,5,5};              // 2*l1+1
constexpr int P_N2[NP]   = {1,3,5, 1,3,3,5, 1,3,5,5};              // 2*l2+1
constexpr int P_NO[NP]   = {1,3,5, 3,1,5,3, 5,3,1,5};              // 2*lo+1
constexpr int P_S1[NP]   = {0,0,0, 128,128,128,128, 512,512,512,512}; // x1 offset
constexpr int P_S2[NP]   = {0,1,4, 0,1,1,4, 0,1,4,4};              // x2 offset
constexpr int P_MOFF[NP] = {0,1,4,9,18,21,36,45,70,85,90};         // M LDS offsets (sizes no*n1, total 115)
constexpr int P_W3J[NP]  = {0,1,10,35,44,53,98,143,168,213,238};   // w3j offsets (sizes n1*n2*no, total 363)

#define YSTRIDE 388   // per-b ylds stride: 3*128+4 (max 3 k-slots resident; pad 4)

struct TPConst {
    float w3j[363];
    float sqa[11];
};

// ---- host-side exact mirror of the reference w3j computation -------------
namespace {

double hfact(int n) { double r = 1.0; for (int i = 2; i <= n; ++i) r *= (double)i; return r; }

void hsu2cg(int j1, int j2, int j3, double* C) {
    const int d2 = 2*j2+1, d3 = 2*j3+1, d1 = 2*j1+1;
    for (int i = 0; i < d1*d2*d3; ++i) C[i] = 0.0;
    for (int m1 = -j1; m1 <= j1; ++m1)
        for (int m2 = -j2; m2 <= j2; ++m2) {
            const int m3 = m1 + m2;
            if (m3 < -j3 || m3 > j3) continue;
            double pref = std::sqrt((2*j3+1) * hfact(j3+j1-j2) * hfact(j3-j1+j2) * hfact(j1+j2-j3) / hfact(j1+j2+j3+1));
            pref *= std::sqrt(hfact(j3+m3)*hfact(j3-m3)*hfact(j1-m1)*hfact(j1+m1)*hfact(j2-m2)*hfact(j2+m2));
            double s = 0.0;
            for (int k = 0; k <= j1+j2-j3; ++k) {
                if (j1-m1-k < 0 || j2+m2-k < 0 || j3-j2+m1+k < 0 || j3-j1-m2+k < 0) continue;
                double d = hfact(k)*hfact(j1+j2-j3-k)*hfact(j1-m1-k)*hfact(j2+m2-k)*hfact(j3-j2+m1+k)*hfact(j3-j1-m2+k);
                s += ((k & 1) ? -1.0 : 1.0) / d;
            }
            C[((j1+m1)*d2 + (j2+m2))*d3 + (j3+m3)] = pref * s;
        }
}

void hrealbasis(int l, std::complex<double>* q) {  // (2l+1)x(2l+1), row-major
    const int d = 2*l+1;
    for (int i = 0; i < d*d; ++i) q[i] = 0.0;
    const double is2 = 1.0 / std::sqrt(2.0);
    for (int m = -l; m < 0; ++m) {
        q[(l+m)*d + (l - m)] = is2;                                  // l+|m| = l-m for m<0
        q[(l+m)*d + (l + m)] = std::complex<double>(0.0, -is2);      // l-|m| = l+m
    }
    q[l*d + l] = 1.0;
    for (int m = 1; m <= l; ++m) {
        const double sgn = (m & 1) ? -1.0 : 1.0;
        q[(l+m)*d + (l + m)] = sgn * is2;
        q[(l+m)*d + (l - m)] = std::complex<double>(0.0, sgn * is2);
    }
    std::complex<double> ph(1.0, 0.0);
    const std::complex<double> mi(0.0, -1.0);
    for (int i = 0; i < l; ++i) ph *= mi;   // (-i)^l
    for (int i = 0; i < d*d; ++i) q[i] *= ph;
}

void hw3j(int l1, int l2, int l3, float* out) {
    const int d1 = 2*l1+1, d2 = 2*l2+1, d3 = 2*l3+1;
    double C[125];
    hsu2cg(l1, l2, l3, C);
    std::complex<double> Q1[25], Q2[25], Q3[25];
    hrealbasis(l1, Q1); hrealbasis(l2, Q2); hrealbasis(l3, Q3);
    double R[125]; double norm2 = 0.0;
    for (int j = 0; j < d1; ++j)
        for (int l = 0; l < d2; ++l)
            for (int m = 0; m < d3; ++m) {
                std::complex<double> s(0.0, 0.0);
                for (int i = 0; i < d1; ++i)
                    for (int k = 0; k < d2; ++k)
                        for (int n = 0; n < d3; ++n)
                            s += Q1[i*d1 + j] * Q2[k*d2 + l] * std::conj(Q3[n*d3 + m]) * C[(i*d2 + k)*d3 + n];
                R[(j*d2 + l)*d3 + m] = s.real();
                norm2 += s.real() * s.real();
            }
    const double inv = 1.0 / std::sqrt(norm2);
    for (int i = 0; i < d1*d2*d3; ++i) out[i] = (float)(R[i] * inv);
}

void fill_const(TPConst& tc) {
    const int L1[NP] = {0,0,0,1,1,1,1,2,2,2,2};
    const int L2[NP] = {0,1,2,0,1,1,2,0,1,2,2};
    const int LO[NP] = {0,1,2,1,0,2,1,2,1,0,2};
    const double den[3] = {384.0, 512.0, 512.0};   // path_normalization='element'
    for (int p = 0; p < NP; ++p) {
        hw3j(L1[p], L2[p], LO[p], tc.w3j + P_W3J[p]);
        tc.sqa[p] = (float)std::sqrt((2.0*LO[p] + 1.0) / den[LO[p]]);
    }
}

}  // namespace

// ---- device: one (path, k-segment) --------------------------------------
// ROUND-4 LESSON (rule #20 at scale): wrapping passes in `#pragma unroll
// for(pass...)` with a huge body made the compiler leave `pass` runtime ->
// every dependent index went runtime -> acc[8][5] landed in SCRATCH
// (VGPR 68, WRITE_SIZE 9.9 GB, 14.4 ms). Everything below is template /
// straight-line so compile-time-ness never depends on unroll heuristics.
template<int P, int K0, int NOK>
__device__ __forceinline__ void tp_segment(
    const float* __restrict__ x1, const float* __restrict__ wsg,
    const float (*__restrict__ Mlds)[116], float* __restrict__ ylds,
    float (&acc)[8][5], long b0, int uy, int g, int cb, int tw)
{
    constexpr int n1 = P_N1[P];

    // Phase B: ylds[b][kl][u] = sum_i M[b][K0+kl][i] * x1[b, s1 + u*n1 + i]
    #pragma unroll
    for (int bb = 0; bb < 8; ++bb) {
        const int b = g*8 + bb;
        const float* xp = x1 + (b0 + b)*1152 + P_S1[P] + uy*n1;
        float xv[5];
        #pragma unroll
        for (int i = 0; i < n1; ++i) xv[i] = xp[i];
        #pragma unroll
        for (int kl = 0; kl < NOK; ++kl) {
            float yv = 0.f;
            #pragma unroll
            for (int i = 0; i < n1; ++i)
                yv += Mlds[b][P_MOFF[P] + (K0 + kl)*n1 + i] * xv[i];
            ylds[b*YSTRIDE + kl*128 + uy] = yv;
        }
    }
    __syncthreads();

    // Phase C: acc[c][K0+kl] += W_P[u][tw*8+c] * y[cb][kl][u]
    {
        const float* yb = ylds + cb*YSTRIDE;
        const float* wp = wsg + P*16384 + tw*8;
        #pragma unroll 2
        for (int u0 = 0; u0 < 128; u0 += 4) {
            float4 yv4[3];
            #pragma unroll
            for (int kl = 0; kl < NOK; ++kl)
                yv4[kl] = *(const float4*)(yb + kl*128 + u0);
            #pragma unroll
            for (int j = 0; j < 4; ++j) {
                const float4 wa = *(const float4*)(wp + (u0 + j)*128);
                const float4 wb = *(const float4*)(wp + (u0 + j)*128 + 4);
                #pragma unroll
                for (int kl = 0; kl < NOK; ++kl) {
                    const float y = (j == 0) ? yv4[kl].x
                                  : (j == 1) ? yv4[kl].y
                                  : (j == 2) ? yv4[kl].z
                                             : yv4[kl].w;
                    acc[0][K0+kl] += wa.x * y;
                    acc[1][K0+kl] += wa.y * y;
                    acc[2][K0+kl] += wa.z * y;
                    acc[3][K0+kl] += wa.w * y;
                    acc[4][K0+kl] += wb.x * y;
                    acc[5][K0+kl] += wb.y * y;
                    acc[6][K0+kl] += wb.z * y;
                    acc[7][K0+kl] += wb.w * y;
                }
            }
        }
    }
    __syncthreads();
}

// ---- device kernel --------------------------------------------------------
// io-major passes (straight-line) + k-split (3+2) of the no=5 paths:
//  - acc[8][no<=5] <= 40 regs live per pass (round 3's acc[8][9]=72 spilled
//    8 floats/thread at cap 128).
//  - ylds stride 644->388 floats; LDS 48640->32256 B -> VGPR-capped
//    16 waves/CU instead of LDS-capped 12.
// VGPR calibration (measured): (256,3)->cap 84: huge spill; plain->132:
// crosses the 128 HW allocation boundary, occupancy halves; (256,2)->128 OK.
__global__ __launch_bounds__(256, 2)
void tp_kernel(const float* __restrict__ x1, const float* __restrict__ x2,
               const float* __restrict__ wsg, float* __restrict__ out, TPConst tc)
{
    __shared__ float Mlds[BT][116];      // per-b M matrices (scaled), 115 used
    __shared__ float ylds[BT * YSTRIDE]; // per-segment y, layout [b][kl][u]

    const int t = threadIdx.x;
    const long b0 = (long)blockIdx.x * BT;

    // Phase A: M_p[b][k][i] = sum_j C_p[i][j][k] * x2[b][s2+j], scaled
    if (t < BT) {
        float x2v[9];
        #pragma unroll
        for (int j = 0; j < 9; ++j) x2v[j] = x2[(b0 + t)*9 + j];
        #pragma unroll
        for (int p = 0; p < NP; ++p) {
            const int n1 = P_N1[p], n2 = P_N2[p], no = P_NO[p];
            const float sqa = tc.sqa[p];
            #pragma unroll
            for (int k = 0; k < no; ++k)
                #pragma unroll
                for (int i = 0; i < n1; ++i) {
                    float m = 0.f;
                    #pragma unroll
                    for (int j = 0; j < n2; ++j)
                        m += tc.w3j[P_W3J[p] + (i*n2 + j)*no + k] * x2v[P_S2[p] + j];
                    Mlds[t][P_MOFF[p] + k*n1 + i] = m * sqa;
                }
        }
    }

    const int uy = t & 127, g = t >> 7;    // phase B: u lane + b group
    const int cb = t >> 4, tw = t & 15;    // phase C: batch + w-octet
    float* op = out + (b0 + cb)*1152;

    __syncthreads();

    // ---- pass 0: io=0 (no=1), paths 0,4,9 --------------------------------
    {
        float acc[8][5];
        #pragma unroll
        for (int c = 0; c < 8; ++c)
            #pragma unroll
            for (int k = 0; k < 5; ++k) acc[c][k] = 0.f;
        tp_segment<0,0,1>(x1, wsg, Mlds, ylds, acc, b0, uy, g, cb, tw);
        tp_segment<4,0,1>(x1, wsg, Mlds, ylds, acc, b0, uy, g, cb, tw);
        tp_segment<9,0,1>(x1, wsg, Mlds, ylds, acc, b0, uy, g, cb, tw);
        *(float4*)(op + tw*8)     = make_float4(acc[0][0], acc[1][0], acc[2][0], acc[3][0]);
        *(float4*)(op + tw*8 + 4) = make_float4(acc[4][0], acc[5][0], acc[6][0], acc[7][0]);
    }

    // ---- pass 1: io=1 (no=3), paths 1,3,6,8 ------------------------------
    {
        float acc[8][5];
        #pragma unroll
        for (int c = 0; c < 8; ++c)
            #pragma unroll
            for (int k = 0; k < 5; ++k) acc[c][k] = 0.f;
        tp_segment<1,0,3>(x1, wsg, Mlds, ylds, acc, b0, uy, g, cb, tw);
        tp_segment<3,0,3>(x1, wsg, Mlds, ylds, acc, b0, uy, g, cb, tw);
        tp_segment<6,0,3>(x1, wsg, Mlds, ylds, acc, b0, uy, g, cb, tw);
        tp_segment<8,0,3>(x1, wsg, Mlds, ylds, acc, b0, uy, g, cb, tw);
        float b1[24];
        #pragma unroll
        for (int c = 0; c < 8; ++c)
            #pragma unroll
            for (int k = 0; k < 3; ++k) b1[c*3 + k] = acc[c][k];
        #pragma unroll
        for (int q = 0; q < 6; ++q)
            *(float4*)(op + 128 + tw*24 + q*4) = *(const float4*)(b1 + q*4);
    }

    // ---- pass 2: io=2 (no=5), paths 2,5,7,10, k-split 3+2 ----------------
    {
        float acc[8][5];
        #pragma unroll
        for (int c = 0; c < 8; ++c)
            #pragma unroll
            for (int k = 0; k < 5; ++k) acc[c][k] = 0.f;
        tp_segment<2,0,3>(x1, wsg, Mlds, ylds, acc, b0, uy, g, cb, tw);
        tp_segment<2,3,2>(x1, wsg, Mlds, ylds, acc, b0, uy, g, cb, tw);
        tp_segment<5,0,3>(x1, wsg, Mlds, ylds, acc, b0, uy, g, cb, tw);
        tp_segment<5,3,2>(x1, wsg, Mlds, ylds, acc, b0, uy, g, cb, tw);
        tp_segment<7,0,3>(x1, wsg, Mlds, ylds, acc, b0, uy, g, cb, tw);
        tp_segment<7,3,2>(x1, wsg, Mlds, ylds, acc, b0, uy, g, cb, tw);
        tp_segment<10,0,3>(x1, wsg, Mlds, ylds, acc, b0, uy, g, cb, tw);
        tp_segment<10,3,2>(x1, wsg, Mlds, ylds, acc, b0, uy, g, cb, tw);
        float b2[40];
        #pragma unroll
        for (int c = 0; c < 8; ++c)
            #pragma unroll
            for (int k = 0; k < 5; ++k) b2[c*5 + k] = acc[c][k];
        #pragma unroll
        for (int q = 0; q < 10; ++q)
            *(float4*)(op + 512 + tw*40 + q*4) = *(const float4*)(b2 + q*4);
    }
}

// ---- launch ---------------------------------------------------------------
extern "C" void kernel_launch(void* const* d_in, const int* in_sizes, int n_in,
                              void* d_out, int out_size, void* d_ws, size_t ws_size,
                              hipStream_t stream) {
    const float* x1  = (const float*)d_in[0];
    const float* x2  = (const float*)d_in[1];
    const float* wsg = (const float*)d_in[2];
    float* out = (float*)d_out;
    const int B = in_sizes[0] / 1152;   // 32768

    TPConst tc;
    fill_const(tc);   // deterministic; identical on every call (graph-capture safe)

    dim3 grid(B / BT), block(256);
    hipLaunchKernelGGL(tp_kernel, grid, block, 0, stream, x1, x2, wsg, out, tc);
}

// Round 6
// 458.970 us; speedup vs baseline: 31.4034x; 2.8912x over previous
//
#include <hip/hip_runtime.h>
#include <cmath>
#include <complex>

#define BT 16   // batch tile per block
#define NP 11   // number of tensor-product paths

// ---- path metadata (compile-time) ----------------------------------------
// paths in reference order: (i1,i2,io) =
// (0,0,0),(0,1,1),(0,2,2),(1,0,1),(1,1,0),(1,1,2),(1,2,1),(2,0,2),(2,1,1),(2,2,0),(2,2,2)
constexpr int P_N1[NP]   = {1,1,1, 3,3,3,3, 5,5,5,5};              // 2*l1+1
constexpr int P_N2[NP]   = {1,3,5, 1,3,3,5, 1,3,5,5};              // 2*l2+1
constexpr int P_NO[NP]   = {1,3,5, 3,1,5,3, 5,3,1,5};              // 2*lo+1
constexpr int P_S1[NP]   = {0,0,0, 128,128,128,128, 512,512,512,512}; // x1 offset
constexpr int P_S2[NP]   = {0,1,4, 0,1,1,4, 0,1,4,4};              // x2 offset
constexpr int P_MOFF[NP] = {0,1,4,9,18,21,36,45,70,85,90};         // M LDS offsets (sizes no*n1, total 115)
constexpr int P_W3J[NP]  = {0,1,10,35,44,53,98,143,168,213,238};   // w3j offsets (sizes n1*n2*no, total 363)

struct TPConst {
    float w3j[363];
    float sqa[11];
};

// ---- host-side exact mirror of the reference w3j computation -------------
namespace {

double hfact(int n) { double r = 1.0; for (int i = 2; i <= n; ++i) r *= (double)i; return r; }

void hsu2cg(int j1, int j2, int j3, double* C) {
    const int d2 = 2*j2+1, d3 = 2*j3+1, d1 = 2*j1+1;
    for (int i = 0; i < d1*d2*d3; ++i) C[i] = 0.0;
    for (int m1 = -j1; m1 <= j1; ++m1)
        for (int m2 = -j2; m2 <= j2; ++m2) {
            const int m3 = m1 + m2;
            if (m3 < -j3 || m3 > j3) continue;
            double pref = std::sqrt((2*j3+1) * hfact(j3+j1-j2) * hfact(j3-j1+j2) * hfact(j1+j2-j3) / hfact(j1+j2+j3+1));
            pref *= std::sqrt(hfact(j3+m3)*hfact(j3-m3)*hfact(j1-m1)*hfact(j1+m1)*hfact(j2-m2)*hfact(j2+m2));
            double s = 0.0;
            for (int k = 0; k <= j1+j2-j3; ++k) {
                if (j1-m1-k < 0 || j2+m2-k < 0 || j3-j2+m1+k < 0 || j3-j1-m2+k < 0) continue;
                double d = hfact(k)*hfact(j1+j2-j3-k)*hfact(j1-m1-k)*hfact(j2+m2-k)*hfact(j3-j2+m1+k)*hfact(j3-j1-m2+k);
                s += ((k & 1) ? -1.0 : 1.0) / d;
            }
            C[((j1+m1)*d2 + (j2+m2))*d3 + (j3+m3)] = pref * s;
        }
}

void hrealbasis(int l, std::complex<double>* q) {  // (2l+1)x(2l+1), row-major
    const int d = 2*l+1;
    for (int i = 0; i < d*d; ++i) q[i] = 0.0;
    const double is2 = 1.0 / std::sqrt(2.0);
    for (int m = -l; m < 0; ++m) {
        q[(l+m)*d + (l - m)] = is2;                                  // l+|m| = l-m for m<0
        q[(l+m)*d + (l + m)] = std::complex<double>(0.0, -is2);      // l-|m| = l+m
    }
    q[l*d + l] = 1.0;
    for (int m = 1; m <= l; ++m) {
        const double sgn = (m & 1) ? -1.0 : 1.0;
        q[(l+m)*d + (l + m)] = sgn * is2;
        q[(l+m)*d + (l - m)] = std::complex<double>(0.0, sgn * is2);
    }
    std::complex<double> ph(1.0, 0.0);
    const std::complex<double> mi(0.0, -1.0);
    for (int i = 0; i < l; ++i) ph *= mi;   // (-i)^l
    for (int i = 0; i < d*d; ++i) q[i] *= ph;
}

void hw3j(int l1, int l2, int l3, float* out) {
    const int d1 = 2*l1+1, d2 = 2*l2+1, d3 = 2*l3+1;
    double C[125];
    hsu2cg(l1, l2, l3, C);
    std::complex<double> Q1[25], Q2[25], Q3[25];
    hrealbasis(l1, Q1); hrealbasis(l2, Q2); hrealbasis(l3, Q3);
    double R[125]; double norm2 = 0.0;
    for (int j = 0; j < d1; ++j)
        for (int l = 0; l < d2; ++l)
            for (int m = 0; m < d3; ++m) {
                std::complex<double> s(0.0, 0.0);
                for (int i = 0; i < d1; ++i)
                    for (int k = 0; k < d2; ++k)
                        for (int n = 0; n < d3; ++n)
                            s += Q1[i*d1 + j] * Q2[k*d2 + l] * std::conj(Q3[n*d3 + m]) * C[(i*d2 + k)*d3 + n];
                R[(j*d2 + l)*d3 + m] = s.real();
                norm2 += s.real() * s.real();
            }
    const double inv = 1.0 / std::sqrt(norm2);
    for (int i = 0; i < d1*d2*d3; ++i) out[i] = (float)(R[i] * inv);
}

void fill_const(TPConst& tc) {
    const int L1[NP] = {0,0,0,1,1,1,1,2,2,2,2};
    const int L2[NP] = {0,1,2,0,1,1,2,0,1,2,2};
    const int LO[NP] = {0,1,2,1,0,2,1,2,1,0,2};
    const double den[3] = {384.0, 512.0, 512.0};   // path_normalization='element'
    for (int p = 0; p < NP; ++p) {
        hw3j(L1[p], L2[p], LO[p], tc.w3j + P_W3J[p]);
        tc.sqa[p] = (float)std::sqrt((2.0*LO[p] + 1.0) / den[LO[p]]);
    }
}

}  // namespace

// ---- device types / helpers ----------------------------------------------
typedef __attribute__((ext_vector_type(8))) short  short8v;   // 8 bf16 (4 VGPRs), MFMA A/B frag
typedef __attribute__((ext_vector_type(4))) float  f32x4;     // MFMA C/D frag
typedef __attribute__((ext_vector_type(4))) unsigned int uint4v;

__device__ __forceinline__ unsigned fbits(float f) { return __builtin_bit_cast(unsigned, f); }
__device__ __forceinline__ float    bitsf(unsigned u) { return __builtin_bit_cast(float, u); }

// hi/lo bf16 split of two floats, packed as (f1<<16 | f0) dwords.
// hi = truncated top-16 (exactly representable); lo = bf16(trunc residual).
// Captured precision ~17 mantissa bits -> relative error ~2^-17 per element.
__device__ __forceinline__ void split2(float f0, float f1, unsigned& h, unsigned& l) {
    const unsigned u0 = fbits(f0), u1 = fbits(f1);
    h = (u0 >> 16) | (u1 & 0xFFFF0000u);
    const float r0 = f0 - bitsf(u0 & 0xFFFF0000u);
    const float r1 = f1 - bitsf(u1 & 0xFFFF0000u);
    l = (fbits(r0) >> 16) | (fbits(r1) & 0xFFFF0000u);
}

// ---- one tensor-product path: phase B (VALU) + phase C (MFMA) -------------
// ROUND-4 LESSON (rule #20): straight-line templated paths only — no
// runtime-dependent indices anywhere near acc.
//
// Phase C GEMM per block: C[w,(b,k)] += sum_u W_p[u,w] * y[b,u,k]
//   mfma_f32_16x16x32_bf16 tiles: M-tile = 16 w (2 per wave), N-tile = 16 b
//   (one per output slot k), K = 4 steps of 32 u. fp32 via hi/lo bf16 split,
//   3 products (Wh*yh + Wh*yl + Wl*yh).
// Assumed A/B lane layout (CDNA 16x16x32 convention): lane l holds
//   A[m = l&15][k = (l>>4)*8 + i], B[k = (l>>4)*8 + i][n = l&15], i=0..7
//   contiguous; C/D: col(n)=lane&15, row(m)=(lane>>4)*4+reg [guide, m89].
// ylds layout [k][b][u] bf16 (hi+lo planes), u-index XOR-swizzled by
// (b&7)<<3: un-swizzled, the 16 b-rows (stride 256 B) of a frag read are a
// 16-way bank conflict; swizzled it's 2-way = free [m136]. Writes stay
// contiguous-permuted 128 B runs (conflict-free).
template<int P>
__device__ __forceinline__ void tp_path(
    const float* __restrict__ x1, const float* __restrict__ wsg,
    const float (*__restrict__ Mlds)[116],
    unsigned short* __restrict__ yhi, unsigned short* __restrict__ ylo,
    f32x4 (&acc)[2][P_NO[P]],
    long b0, int uy, int g, int lane, int wv)
{
    constexpr int n1 = P_N1[P];
    constexpr int no = P_NO[P];

    // Phase B: y[b][u][k] = sum_i M[b][k][i] * x1[b, s1 + u*n1 + i], split+store
    #pragma unroll
    for (int bb = 0; bb < 8; ++bb) {
        const int b = g*8 + bb;
        const float* xp = x1 + (b0 + b)*1152 + P_S1[P] + uy*n1;
        float xv[5];
        #pragma unroll
        for (int i = 0; i < n1; ++i) xv[i] = xp[i];
        const int us = uy ^ ((b & 7) << 3);   // swizzled u index
        #pragma unroll
        for (int k = 0; k < no; ++k) {
            float yv = 0.f;
            #pragma unroll
            for (int i = 0; i < n1; ++i)
                yv += Mlds[b][P_MOFF[P] + k*n1 + i] * xv[i];
            const unsigned ub = fbits(yv);
            const float hif = bitsf(ub & 0xFFFF0000u);
            yhi[(k*16 + b)*128 + us] = (unsigned short)(ub >> 16);
            ylo[(k*16 + b)*128 + us] = (unsigned short)(fbits(yv - hif) >> 16);
        }
    }
    __syncthreads();

    // Phase C: MFMA over 4 K-steps
    {
        const int bC = lane & 15, qC = lane >> 4;
        const float* wpp = wsg + P*16384;
        #pragma unroll
        for (int k4 = 0; k4 < 4; ++k4) {
            const int ubase = k4*32 + qC*8;
            // A-frags: W[u][w] column slices, converted + split in-register.
            // Identical across blocks -> L1/L2-hot; ~64 scalar loads/path/lane.
            short8v Ah[2], Al[2];
            #pragma unroll
            for (int mt = 0; mt < 2; ++mt) {
                const float* ap = wpp + ubase*128 + (wv*32 + mt*16 + bC);
                uint4v hh, ll;
                #pragma unroll
                for (int e = 0; e < 4; ++e) {
                    unsigned h, l;
                    split2(ap[(2*e)*128], ap[(2*e + 1)*128], h, l);
                    hh[e] = h; ll[e] = l;
                }
                Ah[mt] = __builtin_bit_cast(short8v, hh);
                Al[mt] = __builtin_bit_cast(short8v, ll);
            }
            const int uoff = ubase ^ ((bC & 7) << 3);
            #pragma unroll
            for (int k = 0; k < no; ++k) {
                const int ridx = (k*16 + bC)*128 + uoff;
                const short8v Bh = *(const short8v*)(yhi + ridx);
                const short8v Bl = *(const short8v*)(ylo + ridx);
                #pragma unroll
                for (int mt = 0; mt < 2; ++mt) {
                    acc[mt][k] = __builtin_amdgcn_mfma_f32_16x16x32_bf16(Ah[mt], Bh, acc[mt][k], 0, 0, 0);
                    acc[mt][k] = __builtin_amdgcn_mfma_f32_16x16x32_bf16(Ah[mt], Bl, acc[mt][k], 0, 0, 0);
                    acc[mt][k] = __builtin_amdgcn_mfma_f32_16x16x32_bf16(Al[mt], Bh, acc[mt][k], 0, 0, 0);
                }
            }
        }
    }
    __syncthreads();
}

// ---- device kernel --------------------------------------------------------
// io-major straight-line passes (no k-split — round 5 showed it doubles
// FETCH and buys no occupancy). LDS: Mlds 7424 + 2*20480 = 48384 B ->
// 3 blocks/CU. acc = f32x4[2][no] <= 40 regs. (256,2) caps VGPR at 128
// (calibrated: (256,3)->84 huge spill; plain->132 crosses the 128 HW
// allocation boundary and halves residency).
__global__ __launch_bounds__(256, 2)
void tp_kernel(const float* __restrict__ x1, const float* __restrict__ x2,
               const float* __restrict__ wsg, float* __restrict__ out, TPConst tc)
{
    __shared__ float Mlds[BT][116];                      // per-b M matrices (scaled), 115 used
    __shared__ __align__(16) unsigned short yhi[5*16*128];  // y hi-plane, [k][b][u] swizzled
    __shared__ __align__(16) unsigned short ylo[5*16*128];  // y lo-plane

    const int t = threadIdx.x;
    const long b0 = (long)blockIdx.x * BT;

    // Phase A: M_p[b][k][i] = sum_j C_p[i][j][k] * x2[b][s2+j], scaled
    if (t < BT) {
        float x2v[9];
        #pragma unroll
        for (int j = 0; j < 9; ++j) x2v[j] = x2[(b0 + t)*9 + j];
        #pragma unroll
        for (int p = 0; p < NP; ++p) {
            const int n1 = P_N1[p], n2 = P_N2[p], no = P_NO[p];
            const float sqa = tc.sqa[p];
            #pragma unroll
            for (int k = 0; k < no; ++k)
                #pragma unroll
                for (int i = 0; i < n1; ++i) {
                    float m = 0.f;
                    #pragma unroll
                    for (int j = 0; j < n2; ++j)
                        m += tc.w3j[P_W3J[p] + (i*n2 + j)*no + k] * x2v[P_S2[p] + j];
                    Mlds[t][P_MOFF[p] + k*n1 + i] = m * sqa;
                }
        }
    }

    const int uy = t & 127, g = t >> 7;      // phase B roles
    const int lane = t & 63, wv = t >> 6;    // phase C roles: wave + lane
    const int bC = lane & 15, qC = lane >> 4;
    float* opb = out + (b0 + bC)*1152;

    __syncthreads();

    // ---- pass 0: io=0 (no=1), paths 0,4,9 --------------------------------
    {
        f32x4 acc[2][1];
        #pragma unroll
        for (int mt = 0; mt < 2; ++mt) acc[mt][0] = f32x4{0.f, 0.f, 0.f, 0.f};
        tp_path<0>(x1, wsg, Mlds, yhi, ylo, acc, b0, uy, g, lane, wv);
        tp_path<4>(x1, wsg, Mlds, yhi, ylo, acc, b0, uy, g, lane, wv);
        tp_path<9>(x1, wsg, Mlds, yhi, ylo, acc, b0, uy, g, lane, wv);
        // out[b, w] ; lane holds w = wv*32 + mt*16 + qC*4 + r, r=0..3 contiguous
        #pragma unroll
        for (int mt = 0; mt < 2; ++mt)
            *(f32x4*)(opb + wv*32 + mt*16 + qC*4) = acc[mt][0];
    }

    // ---- pass 1: io=1 (no=3), paths 1,3,6,8 ------------------------------
    {
        f32x4 acc[2][3];
        #pragma unroll
        for (int mt = 0; mt < 2; ++mt)
            #pragma unroll
            for (int k = 0; k < 3; ++k) acc[mt][k] = f32x4{0.f, 0.f, 0.f, 0.f};
        tp_path<1>(x1, wsg, Mlds, yhi, ylo, acc, b0, uy, g, lane, wv);
        tp_path<3>(x1, wsg, Mlds, yhi, ylo, acc, b0, uy, g, lane, wv);
        tp_path<6>(x1, wsg, Mlds, yhi, ylo, acc, b0, uy, g, lane, wv);
        tp_path<8>(x1, wsg, Mlds, yhi, ylo, acc, b0, uy, g, lane, wv);
        #pragma unroll
        for (int mt = 0; mt < 2; ++mt)
            #pragma unroll
            for (int r = 0; r < 4; ++r) {
                const int w = wv*32 + mt*16 + qC*4 + r;
                #pragma unroll
                for (int k = 0; k < 3; ++k)
                    opb[128 + w*3 + k] = acc[mt][k][r];
            }
    }

    // ---- pass 2: io=2 (no=5), paths 2,5,7,10 -----------------------------
    {
        f32x4 acc[2][5];
        #pragma unroll
        for (int mt = 0; mt < 2; ++mt)
            #pragma unroll
            for (int k = 0; k < 5; ++k) acc[mt][k] = f32x4{0.f, 0.f, 0.f, 0.f};
        tp_path<2>(x1, wsg, Mlds, yhi, ylo, acc, b0, uy, g, lane, wv);
        tp_path<5>(x1, wsg, Mlds, yhi, ylo, acc, b0, uy, g, lane, wv);
        tp_path<7>(x1, wsg, Mlds, yhi, ylo, acc, b0, uy, g, lane, wv);
        tp_path<10>(x1, wsg, Mlds, yhi, ylo, acc, b0, uy, g, lane, wv);
        #pragma unroll
        for (int mt = 0; mt < 2; ++mt)
            #pragma unroll
            for (int r = 0; r < 4; ++r) {
                const int w = wv*32 + mt*16 + qC*4 + r;
                #pragma unroll
                for (int k = 0; k < 5; ++k)
                    opb[512 + w*5 + k] = acc[mt][k][r];
            }
    }
}

// ---- launch ---------------------------------------------------------------
extern "C" void kernel_launch(void* const* d_in, const int* in_sizes, int n_in,
                              void* d_out, int out_size, void* d_ws, size_t ws_size,
                              hipStream_t stream) {
    const float* x1  = (const float*)d_in[0];
    const float* x2  = (const float*)d_in[1];
    const float* wsg = (const float*)d_in[2];
    float* out = (float*)d_out;
    const int B = in_sizes[0] / 1152;   // 32768

    TPConst tc;
    fill_const(tc);   // deterministic; identical on every call (graph-capture safe)

    dim3 grid(B / BT), block(256);
    hipLaunchKernelGGL(tp_kernel, grid, block, 0, stream, x1, x2, wsg, out, tc);
}